// Round 10
// baseline (72.256 us; speedup 1.0000x reference)
//
#include <hip/hip_runtime.h>

#define H 1024
#define W 1024
#define NB 8
#define TY 4
#define NT 128              /* 2 waves per block */
#define BCOLS 512           /* cols per block */
#define WCOLS 256           /* output cols per wave */
#define LW (WCOLS + 8)      /* 264: 4-col halo each side */

__global__ void ncc_zero(double* acc) { *acc = 0.0; }

__global__ void ncc_finalize(const double* __restrict__ acc, float* __restrict__ out) {
    out[0] = 1.0f - (float)(*acc * (1.0 / 8388608.0));  // 8*1024*1024 pixels
}

__global__ __launch_bounds__(NT) void ncc_main(
    const float* __restrict__ Jg,  // y_pred
    const float* __restrict__ Ig,  // y_true
    double* __restrict__ acc)
{
    __shared__ float vs[NT / 64][5][LW];   // wave-private vertical sums: I,J,II,JJ,IJ
    __shared__ double sred[NT / 64];

    const int b     = blockIdx.x;
    const int y0    = blockIdx.y * TY;
    const int xbase = blockIdx.z * BCOLS;
    const int t     = threadIdx.x;
    const int w     = t >> 6;
    const int lane  = t & 63;
    const int xw    = lane << 2;                 // within-wave col base (0..252)
    const int x0    = xbase + (w << 8) + xw;     // global col

    const float* __restrict__ Ib = Ig + (size_t)b * (H * W);
    const float* __restrict__ Jb = Jg + (size_t)b * (H * W);

    // halo: lanes 0..3 left halo cols, lanes 4..7 right halo cols (one scalar col each)
    const int   wbase = xbase + (w << 8);
    const bool  isH   = (lane < 8);
    const int   hc    = (lane < 4) ? (wbase - 4 + lane) : (wbase + WCOLS + (lane - 4));
    const float mh    = (isH && (unsigned)hc < (unsigned)W) ? 1.0f : 0.0f;
    const int   hcc   = min(max(hc, 0), W - 1);
    const int   hslot = (lane < 4) ? lane : (WCOLS + lane);  // 0..3 / 260..263

    float sI[4]={0,0,0,0}, sJ[4]={0,0,0,0}, sII[4]={0,0,0,0}, sJJ[4]={0,0,0,0}, sIJ[4]={0,0,0,0};
    float hs0=0, hs1=0, hs2=0, hs3=0, hs4=0;

    // ---- pipelined init: rows y0-4 .. y0+4, one row ahead in flight ----
    float4 civ, cjv; float chi = 0, chj = 0, cm;
    {
        const int r  = y0 - 4;
        cm = ((unsigned)r < (unsigned)H) ? 1.0f : 0.0f;
        const int rc = min(max(r, 0), H - 1);
        civ = *(const float4*)(Ib + (size_t)rc * W + x0);
        cjv = *(const float4*)(Jb + (size_t)rc * W + x0);
        if (isH) { chi = Ib[(size_t)rc * W + hcc]; chj = Jb[(size_t)rc * W + hcc]; }
    }
    #pragma unroll 1
    for (int k = -4; k <= 4; ++k) {
        const int   rn  = y0 + ((k < 4) ? (k + 1) : 4);
        const float nm  = ((unsigned)(y0 + k + 1) < (unsigned)H) ? 1.0f : 0.0f;
        const int   rnc = min(max(rn, 0), H - 1);
        float4 niv = *(const float4*)(Ib + (size_t)rnc * W + x0);
        float4 njv = *(const float4*)(Jb + (size_t)rnc * W + x0);
        float  nhi = 0, nhj = 0;
        if (isH) { nhi = Ib[(size_t)rnc * W + hcc]; nhj = Jb[(size_t)rnc * W + hcc]; }

        {
            const float fi[4] = {civ.x * cm, civ.y * cm, civ.z * cm, civ.w * cm};
            const float fj[4] = {cjv.x * cm, cjv.y * cm, cjv.z * cm, cjv.w * cm};
            #pragma unroll
            for (int c = 0; c < 4; ++c) {
                sI[c] += fi[c]; sJ[c] += fj[c];
                sII[c] += fi[c] * fi[c]; sJJ[c] += fj[c] * fj[c]; sIJ[c] += fi[c] * fj[c];
            }
            const float mm = cm * mh;
            const float hi = chi * mm, hj = chj * mm;
            hs0 += hi; hs1 += hj; hs2 += hi * hi; hs3 += hj * hj; hs4 += hi * hj;
        }
        civ = niv; cjv = njv; chi = nhi; chj = nhj; cm = nm;
    }

    // ---- prologue prefetch for the first slide (window y0 -> y0+1) ----
    float4 pia, pja, pis, pjs; float phia = 0, phja = 0, phis = 0, phjs = 0; float pma, pms;
    {
        const int ra = y0 + 5, rs = y0 - 4;
        pma = (ra < H) ? 1.0f : 0.0f;
        pms = (rs >= 0) ? 1.0f : 0.0f;
        const int rca = min(ra, H - 1), rcs = max(rs, 0);
        pia = *(const float4*)(Ib + (size_t)rca * W + x0);
        pja = *(const float4*)(Jb + (size_t)rca * W + x0);
        pis = *(const float4*)(Ib + (size_t)rcs * W + x0);
        pjs = *(const float4*)(Jb + (size_t)rcs * W + x0);
        if (isH) {
            phia = Ib[(size_t)rca * W + hcc]; phja = Jb[(size_t)rca * W + hcc];
            phis = Ib[(size_t)rcs * W + hcc]; phjs = Jb[(size_t)rcs * W + hcc];
        }
    }

    const float inv = 1.0f / 81.0f;
    float accv = 0.0f;

    #pragma unroll 1
    for (int y = y0; y < y0 + TY; ++y) {
        // 1) publish window(y)
        *(float4*)&vs[w][0][4 + xw] = make_float4(sI[0],  sI[1],  sI[2],  sI[3]);
        *(float4*)&vs[w][1][4 + xw] = make_float4(sJ[0],  sJ[1],  sJ[2],  sJ[3]);
        *(float4*)&vs[w][2][4 + xw] = make_float4(sII[0], sII[1], sII[2], sII[3]);
        *(float4*)&vs[w][3][4 + xw] = make_float4(sJJ[0], sJJ[1], sJJ[2], sJJ[3]);
        *(float4*)&vs[w][4][4 + xw] = make_float4(sIJ[0], sIJ[1], sIJ[2], sIJ[3]);
        if (isH) {
            vs[w][0][hslot] = hs0; vs[w][1][hslot] = hs1; vs[w][2][hslot] = hs2;
            vs[w][3][hslot] = hs3; vs[w][4][hslot] = hs4;
        }
        asm volatile("" ::: "memory");

        // 2) issue halo reads only (own cols stay in registers); in-wave DS is in-order
        float4 a0 = *(const float4*)&vs[w][0][xw], c0 = *(const float4*)&vs[w][0][xw + 8];
        float4 a1 = *(const float4*)&vs[w][1][xw], c1 = *(const float4*)&vs[w][1][xw + 8];
        float4 a2 = *(const float4*)&vs[w][2][xw], c2 = *(const float4*)&vs[w][2][xw + 8];
        float4 a3 = *(const float4*)&vs[w][3][xw], c3 = *(const float4*)&vs[w][3][xw + 8];
        float4 a4 = *(const float4*)&vs[w][4][xw], c4 = *(const float4*)&vs[w][4][xw + 8];
        asm volatile("" ::: "memory");

        // 3) snapshot own totals of window(y) before sliding
        const float T0 = sI[0]  + sI[1]  + sI[2]  + sI[3];
        const float T1 = sJ[0]  + sJ[1]  + sJ[2]  + sJ[3];
        const float T2 = sII[0] + sII[1] + sII[2] + sII[3];
        const float T3 = sJJ[0] + sJJ[1] + sJJ[2] + sJJ[3];
        const float T4 = sIJ[0] + sIJ[1] + sIJ[2] + sIJ[3];

        // 4) slide sums to window(y+1) using prefetched rows (covers the LDS round trip)
        {
            const float fa[4] = {pia.x * pma, pia.y * pma, pia.z * pma, pia.w * pma};
            const float ga[4] = {pja.x * pma, pja.y * pma, pja.z * pma, pja.w * pma};
            const float fs[4] = {pis.x * pms, pis.y * pms, pis.z * pms, pis.w * pms};
            const float gs[4] = {pjs.x * pms, pjs.y * pms, pjs.z * pms, pjs.w * pms};
            #pragma unroll
            for (int c = 0; c < 4; ++c) {
                sI[c]  += fa[c] - fs[c];
                sJ[c]  += ga[c] - gs[c];
                sII[c] += fa[c] * fa[c] - fs[c] * fs[c];
                sJJ[c] += ga[c] * ga[c] - gs[c] * gs[c];
                sIJ[c] += fa[c] * ga[c] - fs[c] * gs[c];
            }
            const float hia = phia * (pma * mh), hja = phja * (pma * mh);
            const float his = phis * (pms * mh), hjs = phjs * (pms * mh);
            hs0 += hia - his;
            hs1 += hja - hjs;
            hs2 += hia * hia - his * his;
            hs3 += hja * hja - hjs * hjs;
            hs4 += hia * hja - his * hjs;
        }

        // 5) prefetch rows for the next slide (window y+1 -> y+2)
        {
            const int ra = y + 6, rs = y - 3;
            pma = (ra < H) ? 1.0f : 0.0f;
            pms = (rs >= 0) ? 1.0f : 0.0f;
            const int rca = min(ra, H - 1), rcs = max(rs, 0);
            pia = *(const float4*)(Ib + (size_t)rca * W + x0);
            pja = *(const float4*)(Jb + (size_t)rca * W + x0);
            pis = *(const float4*)(Ib + (size_t)rcs * W + x0);
            pjs = *(const float4*)(Jb + (size_t)rcs * W + x0);
            if (isH) {
                phia = Ib[(size_t)rca * W + hcc]; phja = Jb[(size_t)rca * W + hcc];
                phis = Ib[(size_t)rcs * W + hcc]; phjs = Jb[(size_t)rcs * W + hcc];
            }
        }

        // 6) combine halo + own totals -> 9-tap sums; per-pixel cc for row y
        float h[5][4];
        {
            const float4 aa[5]  = {a0, a1, a2, a3, a4};
            const float4 cc4[5] = {c0, c1, c2, c3, c4};
            const float  TT[5]  = {T0, T1, T2, T3, T4};
            #pragma unroll
            for (int q = 0; q < 5; ++q) {
                const float4 a  = aa[q];
                const float4 cg = cc4[q];
                float s = a.x + a.y + a.z + a.w + cg.x + TT[q];
                h[q][0] = s; s += cg.y - a.x;
                h[q][1] = s; s += cg.z - a.y;
                h[q][2] = s; s += cg.w - a.z;
                h[q][3] = s;
            }
        }
        #pragma unroll
        for (int c = 0; c < 4; ++c) {
            const float uI    = h[0][c] * inv;
            const float uJ    = h[1][c] * inv;
            const float cross = h[4][c] * inv - uI * uJ;
            const float Iv    = h[2][c] * inv - uI * uI;
            const float Jv    = h[3][c] * inv - uJ * uJ;
            accv += cross * rsqrtf(fmaxf(Iv * Jv, 1e-7f));
        }
    }

    // wave reduce (64 lanes) -> LDS -> one atomic per block (cold path)
    #pragma unroll
    for (int off = 32; off > 0; off >>= 1)
        accv += __shfl_down(accv, off);
    if (lane == 0)
        sred[w] = (double)accv;
    __syncthreads();
    if (t == 0) {
        double s = sred[0];
        #pragma unroll
        for (int q = 1; q < NT / 64; ++q) s += sred[q];
        atomicAdd(acc, s);
    }
}

extern "C" void kernel_launch(void* const* d_in, const int* in_sizes, int n_in,
                              void* d_out, int out_size, void* d_ws, size_t ws_size,
                              hipStream_t stream) {
    const float* y_pred = (const float*)d_in[0];  // Ji
    const float* y_true = (const float*)d_in[1];  // Ii
    float* out = (float*)d_out;
    double* accp = (double*)d_ws;

    ncc_zero<<<dim3(1), dim3(1), 0, stream>>>(accp);
    // 8 x 256 x 2 = 4096 blocks x 2 waves = 8192 waves -> 32 waves/CU supplied
    dim3 grid(NB, H / TY, W / BCOLS);
    ncc_main<<<grid, dim3(NT), 0, stream>>>(y_pred, y_true, accp);
    ncc_finalize<<<dim3(1), dim3(1), 0, stream>>>(accp, out);
}